// Round 2
// baseline (2286.830 us; speedup 1.0000x reference)
//
#include <hip/hip_runtime.h>
#include <hip/hip_bf16.h>
#include <math.h>

// Problem constants
// B=4, T=2048, C=1024, H=16, HD=64, M = B*T = 8192
// ws layout (floats): Qh[64][2048][64] | Kh | Vh | Oh  (each 8,388,608 floats; 128MB total)

#define M_TOT   8192
#define C_DIM   1024
#define T_DIM   2048
#define NH      16
#define HD      64
#define BHT     (NH * 4)        // B*H = 64

// ---------------------------------------------------------------------------
// Kernel 1: fused QKV projection.  C_virtual = x @ [Wq | Wk | Wv]  (N = 3072)
// 128x128 block tile, BK=8, 8x8 per thread (split 4+4 columns to kill the
// 4-way LDS bank conflict on B reads), 256 threads.
// Output written directly in head-major layout [B*H, T, 64].
// ---------------------------------------------------------------------------
__global__ __launch_bounds__(256, 2) void qkv_gemm(
    const float* __restrict__ x,
    const float* __restrict__ Wq,
    const float* __restrict__ Wk,
    const float* __restrict__ Wv,
    float* __restrict__ Qh,
    float* __restrict__ Kh,
    float* __restrict__ Vh)
{
    __shared__ float As[8][132];   // [k][m], padded
    __shared__ float Bs[8][132];   // [k][n], padded

    const int tid = threadIdx.x;
    const int m0  = blockIdx.x * 128;
    const int bn  = blockIdx.y;          // 0..23
    const int which = bn >> 3;           // 0=Q,1=K,2=V
    const int nn0 = (bn & 7) * 128;      // column offset within the 1024-wide W

    const float* W   = (which == 0) ? Wq : ((which == 1) ? Wk : Wv);
    float*       out = (which == 0) ? Qh : ((which == 1) ? Kh : Vh);

    const int arow = tid >> 1, aq = tid & 1;   // A tile: 128 rows x 2 quads
    const int brow = tid >> 5, bq = tid & 31;  // B tile: 8 rows x 32 quads

    const float* aptr = x + (size_t)(m0 + arow) * C_DIM + aq * 4;
    const float* bptr = W + (size_t)brow * C_DIM + nn0 + bq * 4;

    const int tx = tid & 15, ty = tid >> 4;

    float acc[8][8];
    #pragma unroll
    for (int i = 0; i < 8; ++i)
        #pragma unroll
        for (int j = 0; j < 8; ++j) acc[i][j] = 0.f;

    float4 av = *(const float4*)(aptr);
    float4 bv = *(const float4*)(bptr);

    for (int kt = 0; kt < 128; ++kt) {
        __syncthreads();
        As[aq * 4 + 0][arow] = av.x;
        As[aq * 4 + 1][arow] = av.y;
        As[aq * 4 + 2][arow] = av.z;
        As[aq * 4 + 3][arow] = av.w;
        *(float4*)&Bs[brow][bq * 4] = bv;
        __syncthreads();

        if (kt + 1 < 128) {  // issue next-tile loads before compute (latency hiding)
            av = *(const float4*)(aptr + (kt + 1) * 8);
            bv = *(const float4*)(bptr + (size_t)(kt + 1) * 8 * C_DIM);
        }

        #pragma unroll
        for (int kk = 0; kk < 8; ++kk) {
            float a[8], b[8];
            #pragma unroll
            for (int i = 0; i < 8; ++i) a[i] = As[kk][ty * 8 + i];
            #pragma unroll
            for (int j = 0; j < 4; ++j) {
                b[j]     = Bs[kk][tx * 4 + j];        // cols nn0 + tx*4 + j
                b[4 + j] = Bs[kk][64 + tx * 4 + j];   // cols nn0 + 64 + tx*4 + j
            }
            #pragma unroll
            for (int i = 0; i < 8; ++i)
                #pragma unroll
                for (int j = 0; j < 8; ++j)
                    acc[i][j] = fmaf(a[i], b[j], acc[i][j]);
        }
    }

    // write head-major: [(b*16+h)*2048 + t]*64 + d
    // group A: cols nn0 + tx*4     -> head ha = nn0>>6,     d0 = tx*4
    // group B: cols nn0 + 64 + tx*4 -> head ha+1,           d0 = tx*4
    const int ha = nn0 >> 6;         // even head index (nn0 multiple of 128)
    const int d0 = tx * 4;
    #pragma unroll
    for (int i = 0; i < 8; ++i) {
        const int m = m0 + ty * 8 + i;
        const int b = m >> 11, t = m & 2047;
        float* opA = out + (size_t)((b * NH + ha    ) * T_DIM + t) * HD + d0;
        float* opB = out + (size_t)((b * NH + ha + 1) * T_DIM + t) * HD + d0;
        *(float4*)opA = make_float4(acc[i][0], acc[i][1], acc[i][2], acc[i][3]);
        *(float4*)opB = make_float4(acc[i][4], acc[i][5], acc[i][6], acc[i][7]);
    }
}

// ---------------------------------------------------------------------------
// Kernel 2: causal flash attention, fp32.
// grid (T/256, B*H), 256 threads; one query row per thread.
// K/V tiles (64x64) staged in LDS; per-thread online softmax.
// (Known-suspect for LDS-bound behavior; kept as measurement target.)
// ---------------------------------------------------------------------------
__global__ __launch_bounds__(256, 2) void attn_kernel(
    const float* __restrict__ Qh,
    const float* __restrict__ Kh,
    const float* __restrict__ Vh,
    float* __restrict__ Oh)
{
    __shared__ float Ks[64][64];
    __shared__ float Vs[64][64];

    const int tid = threadIdx.x;
    const int bh  = blockIdx.y;
    const int r0  = blockIdx.x * 256;
    const int row = r0 + tid;

    const float* qp = Qh + ((size_t)bh * T_DIM + row) * HD;
    float q[64];
    #pragma unroll
    for (int d = 0; d < 64; ++d) q[d] = qp[d];

    float o[64];
    #pragma unroll
    for (int d = 0; d < 64; ++d) o[d] = 0.f;
    float mx = -INFINITY, l = 0.f;

    const float* kb = Kh + (size_t)bh * T_DIM * HD;
    const float* vb = Vh + (size_t)bh * T_DIM * HD;
    const int ntiles = (r0 >> 6) + 4;

    for (int kt = 0; kt < ntiles; ++kt) {
        __syncthreads();
        const float4* ksrc = (const float4*)(kb + (size_t)kt * 64 * 64);
        const float4* vsrc = (const float4*)(vb + (size_t)kt * 64 * 64);
        #pragma unroll
        for (int u = 0; u < 4; ++u) {
            ((float4*)&Ks[0][0])[u * 256 + tid] = ksrc[u * 256 + tid];
            ((float4*)&Vs[0][0])[u * 256 + tid] = vsrc[u * 256 + tid];
        }
        __syncthreads();

        int kmax = row - kt * 64 + 1;
        if (kmax > 64) kmax = 64;
        for (int kk = 0; kk < kmax; ++kk) {
            float s0 = 0.f, s1 = 0.f, s2 = 0.f, s3 = 0.f;
            #pragma unroll
            for (int d = 0; d < 64; d += 4) {
                s0 = fmaf(q[d],     Ks[kk][d],     s0);
                s1 = fmaf(q[d + 1], Ks[kk][d + 1], s1);
                s2 = fmaf(q[d + 2], Ks[kk][d + 2], s2);
                s3 = fmaf(q[d + 3], Ks[kk][d + 3], s3);
            }
            float s = ((s0 + s1) + (s2 + s3)) * 0.125f;  // 1/sqrt(64)
            if (s > mx) {  // rare: rescale only on new max
                float c = __expf(mx - s);
                #pragma unroll
                for (int d = 0; d < 64; ++d) o[d] *= c;
                l *= c;
                mx = s;
            }
            float w = __expf(s - mx);
            l += w;
            #pragma unroll
            for (int d = 0; d < 64; ++d) o[d] = fmaf(w, Vs[kk][d], o[d]);
        }
    }

    const float inv = 1.0f / l;
    float* op = Oh + ((size_t)bh * T_DIM + row) * HD;
    #pragma unroll
    for (int d = 0; d < 64; ++d) op[d] = o[d] * inv;
}

// ---------------------------------------------------------------------------
// Kernel 3: output projection  out = Oh(head-major) @ Wc + bc
// Same GEMM structure (split 4+4 columns); A reads gather from head-major.
// ---------------------------------------------------------------------------
__global__ __launch_bounds__(256, 2) void out_gemm(
    const float* __restrict__ Oh,
    const float* __restrict__ Wc,
    const float* __restrict__ bc,
    float* __restrict__ out)
{
    __shared__ float As[8][132];
    __shared__ float Bs[8][132];

    const int tid = threadIdx.x;
    const int m0  = blockIdx.x * 128;
    const int nn0 = blockIdx.y * 128;

    const int arow = tid >> 1, aq = tid & 1;
    const int brow = tid >> 5, bq = tid & 31;

    const int am = m0 + arow;
    const size_t aBase = (size_t)((am >> 11) * NH) * (size_t)(T_DIM * HD)
                       + (size_t)(am & 2047) * HD;
    const float* bptr = Wc + (size_t)brow * C_DIM + nn0 + bq * 4;

    const int tx = tid & 15, ty = tid >> 4;

    float acc[8][8];
    #pragma unroll
    for (int i = 0; i < 8; ++i)
        #pragma unroll
        for (int j = 0; j < 8; ++j) acc[i][j] = 0.f;

    int kcol = aq * 4;
    float4 av = *(const float4*)(Oh + aBase + (size_t)(kcol >> 6) * (T_DIM * HD) + (kcol & 63));
    float4 bv = *(const float4*)(bptr);

    for (int kt = 0; kt < 128; ++kt) {
        __syncthreads();
        As[aq * 4 + 0][arow] = av.x;
        As[aq * 4 + 1][arow] = av.y;
        As[aq * 4 + 2][arow] = av.z;
        As[aq * 4 + 3][arow] = av.w;
        *(float4*)&Bs[brow][bq * 4] = bv;
        __syncthreads();

        if (kt + 1 < 128) {
            kcol = (kt + 1) * 8 + aq * 4;
            av = *(const float4*)(Oh + aBase + (size_t)(kcol >> 6) * (T_DIM * HD) + (kcol & 63));
            bv = *(const float4*)(bptr + (size_t)(kt + 1) * 8 * C_DIM);
        }

        #pragma unroll
        for (int kk = 0; kk < 8; ++kk) {
            float a[8], b[8];
            #pragma unroll
            for (int i = 0; i < 8; ++i) a[i] = As[kk][ty * 8 + i];
            #pragma unroll
            for (int j = 0; j < 4; ++j) {
                b[j]     = Bs[kk][tx * 4 + j];
                b[4 + j] = Bs[kk][64 + tx * 4 + j];
            }
            #pragma unroll
            for (int i = 0; i < 8; ++i)
                #pragma unroll
                for (int j = 0; j < 8; ++j)
                    acc[i][j] = fmaf(a[i], b[j], acc[i][j]);
        }
    }

    const int col0 = nn0 + tx * 4;       // group A cols; group B at col0+64
    float bias[8];
    #pragma unroll
    for (int j = 0; j < 4; ++j) {
        bias[j]     = bc[col0 + j];
        bias[4 + j] = bc[col0 + 64 + j];
    }

    #pragma unroll
    for (int i = 0; i < 8; ++i) {
        const int m = m0 + ty * 8 + i;
        float* op = out + (size_t)m * C_DIM;
        *(float4*)(op + col0)      = make_float4(acc[i][0] + bias[0], acc[i][1] + bias[1],
                                                 acc[i][2] + bias[2], acc[i][3] + bias[3]);
        *(float4*)(op + col0 + 64) = make_float4(acc[i][4] + bias[4], acc[i][5] + bias[5],
                                                 acc[i][6] + bias[6], acc[i][7] + bias[7]);
    }
}

// ---------------------------------------------------------------------------
extern "C" void kernel_launch(void* const* d_in, const int* in_sizes, int n_in,
                              void* d_out, int out_size, void* d_ws, size_t ws_size,
                              hipStream_t stream)
{
    const float* x  = (const float*)d_in[0];
    const float* Wq = (const float*)d_in[1];
    const float* Wk = (const float*)d_in[2];
    const float* Wv = (const float*)d_in[3];
    const float* Wc = (const float*)d_in[4];
    const float* bc = (const float*)d_in[5];
    float* out = (float*)d_out;

    float* ws = (float*)d_ws;
    const size_t PLANE = (size_t)M_TOT * C_DIM;  // 8,388,608 floats
    float* Qh = ws;
    float* Kh = ws + PLANE;
    float* Vh = ws + 2 * PLANE;
    float* Oh = ws + 3 * PLANE;

    {
        dim3 grid(M_TOT / 128, 24);   // 24 = 3 * (1024/128)
        qkv_gemm<<<grid, 256, 0, stream>>>(x, Wq, Wk, Wv, Qh, Kh, Vh);
    }
    {
        dim3 grid(T_DIM / 256, BHT);  // (8, 64)
        attn_kernel<<<grid, 256, 0, stream>>>(Qh, Kh, Vh, Oh);
    }
    {
        dim3 grid(M_TOT / 128, C_DIM / 128);  // (64, 8)
        out_gemm<<<grid, 256, 0, stream>>>(Oh, Wc, bc, out);
    }
}